// Round 8
// baseline (1685.900 us; speedup 1.0000x reference)
//
#include <hip/hip_runtime.h>
#include <stdint.h>

// NARM fused pipeline v8 for MI355X (gfx950).
// Overlap with guaranteed 1 block/CU: 1024-thread blocks (16 waves = 4/SIMD;
// VGPR ~100 > 64 forbids a second co-resident block).
//   k_pre  : zeros (carry slot, cum) + A1/A2 -> bf16 + FULL xcast
//   k_chunk (grid 128, 1024 thr), launched per chunk c (tc=50):
//     blocks  0..63 : merged dual-GRU scan of chunk c for batch-group bid
//     blocks 64..127: score+cum epilogue of chunk c-1 (hidden under scan)
//   k_epi  : epilogue of the last chunk
// Fragment layout: off(t,b,k) = t*131072 + (b>>4)*2048 + (k>>3)*128 + (b&15)*8 + (k&7)

typedef __attribute__((ext_vector_type(8))) short short8;
typedef __attribute__((ext_vector_type(4))) float float4v;

#define TC  50
#define NCH 4

#define LDS_BARRIER() asm volatile("s_waitcnt lgkmcnt(0)\n\ts_barrier" ::: "memory")

__device__ inline float bf2f(unsigned short u){
  union { unsigned int i; float f; } v; v.i = ((unsigned int)u) << 16; return v.f;
}
__device__ inline unsigned short f2bf(float f){
  union { float f; unsigned int i; } v; v.f = f;
  unsigned int x = v.i;
  return (unsigned short)((x + 0x7fffu + ((x >> 16) & 1u)) >> 16);
}
__device__ inline float sigm(float x){ return __builtin_amdgcn_rcpf(1.0f + __expf(-x)); }

// ================= scan body (one GRU, 8 waves = tid512 0..511) =============
__device__ __forceinline__ void scan_body(
    unsigned short* hb,                      // LDS, 2*2048 shorts (this GRU's)
    const unsigned short* __restrict__ xb,
    const float* __restrict__ Wih, const float* __restrict__ Whh,
    const float* __restrict__ bih, const float* __restrict__ bhh,
    unsigned short* __restrict__ wrseq,      // full-T sequence buffer
    const unsigned short* __restrict__ prevslot, // carry slice (t pre-applied)
    int t0, int bg, int tid512)
{
  int w = tid512 >> 6, L = tid512 & 63, l15 = L & 15, q = L >> 4;
  int col = w * 16 + l15;
  int cch = w * 2 + (l15 >> 3);
  int cj  = l15 & 7;

  short8 Wi[3][4], Wh[3][4];
  #pragma unroll
  for (int G = 0; G < 3; G++) {
    int row = G * 128 + col;
    #pragma unroll
    for (int kf = 0; kf < 4; kf++) {
      const float4* p0 = (const float4*)(Wih + (size_t)row * 128 + kf * 32 + q * 8);
      const float4* p1 = (const float4*)(Whh + (size_t)row * 128 + kf * 32 + q * 8);
      float4 a0 = p0[0], a1 = p0[1], b0f = p1[0], b1f = p1[1];
      short8 si, sh;
      si[0]=(short)f2bf(a0.x); si[1]=(short)f2bf(a0.y); si[2]=(short)f2bf(a0.z); si[3]=(short)f2bf(a0.w);
      si[4]=(short)f2bf(a1.x); si[5]=(short)f2bf(a1.y); si[6]=(short)f2bf(a1.z); si[7]=(short)f2bf(a1.w);
      sh[0]=(short)f2bf(b0f.x); sh[1]=(short)f2bf(b0f.y); sh[2]=(short)f2bf(b0f.z); sh[3]=(short)f2bf(b0f.w);
      sh[4]=(short)f2bf(b1f.x); sh[5]=(short)f2bf(b1f.y); sh[6]=(short)f2bf(b1f.z); sh[7]=(short)f2bf(b1f.w);
      Wi[G][kf] = si; Wh[G][kf] = sh;
    }
  }
  float br  = bih[col]       + bhh[col];
  float bz  = bih[128 + col] + bhh[128 + col];
  float bin = bih[256 + col];               // bhh_n stays inside r*( ) (PyTorch GRU)
  float bnh = bhh[256 + col];

  float hold[4];
  #pragma unroll
  for (int r = 0; r < 4; r++) {
    int m = q * 4 + r;
    unsigned short u = prevslot[(size_t)bg * 2048 + cch * 128 + m * 8 + cj];
    hold[r] = bf2f(u);
    hb[cch * 128 + m * 8 + cj] = u;
  }

  short8 x2[2][4];
  const unsigned short* xlane = xb + (size_t)bg * 2048 + q * 128 + l15 * 8;
  {
    const unsigned short* px = xlane + (size_t)t0 * 131072;
    #pragma unroll
    for (int kf = 0; kf < 4; kf++) x2[0][kf] = *(const short8*)(px + kf * 512);
    const unsigned short* py = xlane + (size_t)(t0 + 1) * 131072;
    #pragma unroll
    for (int kf = 0; kf < 4; kf++) x2[1][kf] = *(const short8*)(py + kf * 512);
  }
  __syncthreads();

  unsigned short* opq = wrseq + (size_t)t0 * 131072 + (size_t)bg * 2048 + cch * 128 + q * 32 + cj;
  unsigned int* hbw = (unsigned int*)hb;
  int wdw = (2 * w + (l15 >> 3)) * 64 + ((l15 & 6) >> 1);
  bool wlane = (L & 1) == 0;

  auto step = [&](int s, int pin, int pout) {
    short8 Ah[4];
    #pragma unroll
    for (int kf = 0; kf < 4; kf++)
      Ah[kf] = *(const short8*)&hb[pin * 2048 + (kf * 4 + q) * 128 + l15 * 8];

    // h-side MFMAs first (critical path)
    float4v rh = (float4v){0.f,0.f,0.f,0.f}, zh = rh, nh = rh;
    #pragma unroll
    for (int kf = 0; kf < 4; kf++) rh = __builtin_amdgcn_mfma_f32_16x16x32_bf16(Ah[kf], Wh[0][kf], rh, 0,0,0);
    #pragma unroll
    for (int kf = 0; kf < 4; kf++) zh = __builtin_amdgcn_mfma_f32_16x16x32_bf16(Ah[kf], Wh[1][kf], zh, 0,0,0);
    #pragma unroll
    for (int kf = 0; kf < 4; kf++) nh = __builtin_amdgcn_mfma_f32_16x16x32_bf16(Ah[kf], Wh[2][kf], nh, 0,0,0);

    float4v rx = (float4v){0.f,0.f,0.f,0.f}, zx = rx, nx = rx;
    #pragma unroll
    for (int kf = 0; kf < 4; kf++) rx = __builtin_amdgcn_mfma_f32_16x16x32_bf16(x2[pin][kf], Wi[0][kf], rx, 0,0,0);
    #pragma unroll
    for (int kf = 0; kf < 4; kf++) zx = __builtin_amdgcn_mfma_f32_16x16x32_bf16(x2[pin][kf], Wi[1][kf], zx, 0,0,0);
    #pragma unroll
    for (int kf = 0; kf < 4; kf++) nx = __builtin_amdgcn_mfma_f32_16x16x32_bf16(x2[pin][kf], Wi[2][kf], nx, 0,0,0);

    // refill this x buffer for step s+2 (clamped; reads stay in valid xb)
    {
      int t2 = t0 + (s + 2 < TC ? s + 2 : TC - 1);
      const unsigned short* px = xlane + (size_t)t2 * 131072;
      #pragma unroll
      for (int kf = 0; kf < 4; kf++) x2[pin][kf] = *(const short8*)(px + kf * 512);
    }

    unsigned int* hbo = hbw + pout * 1024 + wdw;
    #pragma unroll
    for (int r = 0; r < 4; r++) {
      float er = __expf(-(rh[r] + rx[r] + br));
      float ez = __expf(-(zh[r] + zx[r] + bz));
      float pr = 1.0f + er, pz = 1.0f + ez;
      float inv = __builtin_amdgcn_rcpf(pr * pz);
      float rr = pz * inv;
      float zz = pr * inv;
      float y  = nx[r] + bin + rr * (nh[r] + bnh);
      float em = __expf(-2.0f * y);
      float nn = 2.0f * __builtin_amdgcn_rcpf(1.0f + em) - 1.0f;
      float hn = nn + zz * (hold[r] - nn);
      hold[r] = hn;
      unsigned short hu = f2bf(hn);
      opq[r * 8] = hu;
      unsigned int hv = (unsigned int)hu;
      unsigned int ov = (unsigned int)__shfl_xor((int)hv, 1);
      if (wlane) hbo[(4 * q + r) * 4] = hv | (ov << 16);
    }
    opq += 131072;
    LDS_BARRIER();
  };

  for (int s = 0; s < TC; s += 2) { step(s, 0, 1); step(s + 1, 1, 0); }
}

// ================= epilogue: score + cum for chunk e, one bg, 16 waves =======
__device__ __forceinline__ void epilogue_body(
    float* scF4, unsigned short* hlL,        // LDS: 4*800 floats, 8*2048 shorts
    const unsigned short* __restrict__ hl_seq,
    const unsigned short* __restrict__ hg_seq,
    const unsigned short* __restrict__ a12,
    const float* __restrict__ v1,
    const int* __restrict__ lengths,
    float* __restrict__ cum, float* __restrict__ out,
    int e, int bg, int tid)
{
  int w = tid >> 6, L = tid & 63, l15 = L & 15, q = L >> 4;
  int cg = w & 3;                // column group: n-tiles {2cg, 2cg+1}
  int tg = w >> 2;               // t offset, stride 4
  int t0g = e * TC;

  // register-resident B-fragments (A1^T, A2^T) for this wave's 2 n-tiles
  short8 B1[2][4], B2[2][4];
  float v1v[2];
  #pragma unroll
  for (int ntl = 0; ntl < 2; ntl++) {
    int g = (2 * cg + ntl) * 16 + l15;
    #pragma unroll
    for (int kf = 0; kf < 4; kf++) {
      B1[ntl][kf] = *(const short8*)(a12 + (size_t)g * 128 + kf * 32 + q * 8);
      B2[ntl][kf] = *(const short8*)(a12 + 16384 + (size_t)g * 128 + kf * 32 + q * 8);
    }
    v1v[ntl] = v1[g];
  }

  // score phase: t = tg, tg+4, ...
  for (int t = tg; t < TC; t += 4) {
    size_t base = (size_t)(t0g + t) * 131072 + (size_t)bg * 2048 + q * 128 + l15 * 8;
    float4v acc[2];
    acc[0] = (float4v){0.f,0.f,0.f,0.f}; acc[1] = acc[0];
    {
      short8 F[4];
      #pragma unroll
      for (int kf = 0; kf < 4; kf++) F[kf] = *(const short8*)(hl_seq + base + kf * 512);
      #pragma unroll
      for (int ntl = 0; ntl < 2; ntl++)
        #pragma unroll
        for (int kf = 0; kf < 4; kf++)
          acc[ntl] = __builtin_amdgcn_mfma_f32_16x16x32_bf16(F[kf], B1[ntl][kf], acc[ntl], 0, 0, 0);
    }
    {
      short8 F[4];
      #pragma unroll
      for (int kf = 0; kf < 4; kf++) F[kf] = *(const short8*)(hg_seq + base + kf * 512);
      #pragma unroll
      for (int ntl = 0; ntl < 2; ntl++)
        #pragma unroll
        for (int kf = 0; kf < 4; kf++)
          acc[ntl] = __builtin_amdgcn_mfma_f32_16x16x32_bf16(F[kf], B2[ntl][kf], acc[ntl], 0, 0, 0);
    }
    #pragma unroll
    for (int r = 0; r < 4; r++) {
      float s = v1v[0] * sigm(acc[0][r]) + v1v[1] * sigm(acc[1][r]);
      s += __shfl_xor(s, 1, 16);
      s += __shfl_xor(s, 2, 16);
      s += __shfl_xor(s, 4, 16);
      s += __shfl_xor(s, 8, 16);
      if (l15 == 0) scF4[cg * 800 + t * 16 + q * 4 + r] = s;
    }
  }
  __syncthreads();
  for (int i = tid; i < TC * 16; i += 1024)
    scF4[i] = scF4[i] + scF4[800 + i] + scF4[1600 + i] + scF4[2400 + i];

  // cum phase: 2048 (b,j) states over 1024 threads (2 each)
  float cacc[2]; int capv[2], bl2[2], j2[2], bidx[2], fj2[2];
  #pragma unroll
  for (int k = 0; k < 2; k++) {
    int pi = tid + k * 1024;
    int bl = pi & 15, j = (pi >> 4) & 127;
    bl2[k] = bl; j2[k] = j;
    int b = bg * 16 + bl; bidx[k] = b;
    cacc[k] = cum[(size_t)b * 128 + j];
    capv[k] = lengths[b] - 4;
    fj2[k] = (j >> 3) * 128 + bl * 8 + (j & 7);
  }
  for (int seg = 0; seg < TC; seg += 8) {
    int len = (TC - seg < 8) ? (TC - seg) : 8;
    __syncthreads();                         // also orders scF4 reduce (1st iter)
    for (int f8 = tid; f8 < len * 256; f8 += 1024) {
      int tt = f8 >> 8, idx = f8 & 255;
      *(short8*)&hlL[tt * 2048 + idx * 8] =
          *(const short8*)(hl_seq + (size_t)(t0g + seg + tt) * 131072 + (size_t)bg * 2048 + idx * 8);
    }
    __syncthreads();
    for (int tt = 0; tt < len; tt++) {
      int t = seg + tt;
      #pragma unroll
      for (int k = 0; k < 2; k++) {
        float h = bf2f(hlL[tt * 2048 + fj2[k]]);
        cacc[k] += scF4[t * 16 + bl2[k]] * h;
        int d = (t0g + t) - capv[k];
        if ((unsigned)d < 4u) {
          float hgv = bf2f(hg_seq[(size_t)(t0g + t) * 131072 + (size_t)bg * 2048 + fj2[k]]);
          out[((size_t)bidx[k] * 4 + d) * 128 + j2[k]] = cacc[k] + hgv;
        }
      }
    }
  }
  #pragma unroll
  for (int k = 0; k < 2; k++)
    cum[(size_t)bidx[k] * 128 + j2[k]] = cacc[k];
}

// ================= K_pre: zeros + a12 cast + FULL xcast ======================
__global__ __launch_bounds__(512) void k_pre(const float* __restrict__ x,
                                             unsigned short* __restrict__ xb,
                                             unsigned short* zslot, float* cum,
                                             const float* A1, const float* A2,
                                             unsigned short* a12)
{
  int i = blockIdx.x * 512 + threadIdx.x;   // grid 256 -> 131072 threads
  zslot[i] = 0;
  cum[i] = 0.0f;
  if (i < 32768) a12[i] = f2bf((i < 16384) ? A1[i] : A2[i - 16384]);
  for (int i8 = i; i8 < 200 * 16384; i8 += 131072) {
    int t = i8 >> 14, rem = i8 & 16383, b = rem >> 4, chn = rem & 15;
    const float4* xf = (const float4*)(x + (size_t)t * 131072 + (size_t)b * 128 + chn * 8);
    float4 a = xf[0], bb = xf[1];
    short8 o;
    o[0]=(short)f2bf(a.x); o[1]=(short)f2bf(a.y); o[2]=(short)f2bf(a.z); o[3]=(short)f2bf(a.w);
    o[4]=(short)f2bf(bb.x); o[5]=(short)f2bf(bb.y); o[6]=(short)f2bf(bb.z); o[7]=(short)f2bf(bb.w);
    *(short8*)(xb + (size_t)t * 131072 + (size_t)(b >> 4) * 2048 + chn * 128 + (b & 15) * 8) = o;
  }
}

// ================= K_chunk: scan(c) on blocks 0..63, epilogue(c-1) 64..127 ===
__global__ __launch_bounds__(1024) void k_chunk(
    const unsigned short* __restrict__ xb,
    const float* __restrict__ Wih_g, const float* __restrict__ Whh_g,
    const float* __restrict__ bih_g, const float* __restrict__ bhh_g,
    const float* __restrict__ Wih_l, const float* __restrict__ Whh_l,
    const float* __restrict__ bih_l, const float* __restrict__ bhh_l,
    const unsigned short* __restrict__ a12, const float* __restrict__ v1,
    const int* __restrict__ lengths, float* __restrict__ cum, float* __restrict__ out,
    unsigned short* hl, unsigned short* hg, const unsigned short* zslot, int c)
{
  __shared__ __align__(16) char smem[49152];
  int bid = blockIdx.x, tid = threadIdx.x;

  if (bid < 64) {
    int gru = tid >> 9;                     // waves 0-7: g, 8-15: l
    int tid512 = tid & 511;
    int bg = bid;
    int t0 = c * TC;
    unsigned short* hb = (unsigned short*)smem + gru * 4096;  // 2 pingpong x 2048
    unsigned short* wrseq = gru ? hl : hg;
    const unsigned short* prevslot =
        (c == 0) ? zslot : (wrseq + (size_t)(t0 - 1) * 131072);
    if (gru) scan_body(hb, xb, Wih_l, Whh_l, bih_l, bhh_l, wrseq, prevslot, t0, bg, tid512);
    else     scan_body(hb, xb, Wih_g, Whh_g, bih_g, bhh_g, wrseq, prevslot, t0, bg, tid512);
  } else {
    if (c == 0) return;
    float* scF4 = (float*)smem;                              // 4*800 floats
    unsigned short* hlL = (unsigned short*)(smem + 12800);   // 8*2048 shorts
    epilogue_body(scF4, hlL, hl, hg, a12, v1, lengths, cum, out, c - 1, bid - 64, tid);
  }
}

// ================= K_epi: last chunk's epilogue ==============================
__global__ __launch_bounds__(1024) void k_epi(
    const unsigned short* __restrict__ a12, const float* __restrict__ v1,
    const int* __restrict__ lengths, float* __restrict__ cum, float* __restrict__ out,
    const unsigned short* __restrict__ hl, const unsigned short* __restrict__ hg, int e)
{
  __shared__ __align__(16) char smem[49152];
  float* scF4 = (float*)smem;
  unsigned short* hlL = (unsigned short*)(smem + 12800);
  epilogue_body(scF4, hlL, hl, hg, a12, v1, lengths, cum, out, e, blockIdx.x, threadIdx.x);
}

// ---------------- launch ----------------
extern "C" void kernel_launch(void* const* d_in, const int* in_sizes, int n_in,
                              void* d_out, int out_size, void* d_ws, size_t ws_size,
                              hipStream_t stream)
{
  const float* x     = (const float*)d_in[0];
  const int* lengths = (const int*)d_in[1];
  const float* Wih_g = (const float*)d_in[2];
  const float* Whh_g = (const float*)d_in[3];
  const float* bih_g = (const float*)d_in[4];
  const float* bhh_g = (const float*)d_in[5];
  const float* Wih_l = (const float*)d_in[6];
  const float* Whh_l = (const float*)d_in[7];
  const float* bih_l = (const float*)d_in[8];
  const float* bhh_l = (const float*)d_in[9];
  const float* A1    = (const float*)d_in[10];
  const float* A2    = (const float*)d_in[11];
  const float* v1    = (const float*)d_in[12];
  float* out = (float*)d_out;

  const size_t SEQ = (size_t)200 * 1024 * 128 * 2;  // 52.4 MB each
  size_t need = 65536 + 524288 + 262144 + 3 * SEQ;  // a12 + cum + zslot + xb/hl/hg
  if (need > ws_size) return;                       // ws proven >= need (R2-R6)

  char* wsb = (char*)d_ws;
  size_t o = 0;
  unsigned short* a12  = (unsigned short*)(wsb + o); o += 65536;
  float* cum           = (float*)(wsb + o);          o += 524288;
  unsigned short* zslot= (unsigned short*)(wsb + o); o += 262144;
  unsigned short* xb   = (unsigned short*)(wsb + o); o += SEQ;
  unsigned short* hl   = (unsigned short*)(wsb + o); o += SEQ;
  unsigned short* hg   = (unsigned short*)(wsb + o); o += SEQ;

  k_pre<<<256, 512, 0, stream>>>(x, xb, zslot, cum, A1, A2, a12);
  for (int c = 0; c < NCH; c++) {
    k_chunk<<<128, 1024, 0, stream>>>(xb, Wih_g, Whh_g, bih_g, bhh_g,
                                      Wih_l, Whh_l, bih_l, bhh_l,
                                      a12, v1, lengths, cum, out, hl, hg, zslot, c);
  }
  k_epi<<<64, 1024, 0, stream>>>(a12, v1, lengths, cum, out, hl, hg, NCH - 1);
}

// Round 9
// 483.079 us; speedup vs baseline: 3.4899x; 3.4899x over previous
//
#include <hip/hip_runtime.h>
#include <stdint.h>

// NARM fused pipeline v9 for MI355X (gfx950).
// Proven R6 scan (tc=200, 128 blocks x 512thr) + restructured epilogue:
//   k_pre : zero carry slots + A1/A2 -> bf16 + full xcast (fragment layout)
//   k_scan: dual-GRU recurrence (R6 verbatim: fragment layout, reg weights,
//           conflict-free LDS h, x prefetch 2-deep, LDS_BARRIER)
//   k_ep1 : 256 blocks = 64 bg x 4 t-ranges: fused score (reg A-frags,
//           4-way col split) + range-local cumsum + capture + range sums R
//   k_ep2 : add prefix of R to captured outputs (cumsum decomposition)
// Fragment layout: off(t,b,k) = t*131072 + (b>>4)*2048 + (k>>3)*128 + (b&15)*8 + (k&7)

typedef __attribute__((ext_vector_type(8))) short short8;
typedef __attribute__((ext_vector_type(4))) float float4v;

#define LDS_BARRIER() asm volatile("s_waitcnt lgkmcnt(0)\n\ts_barrier" ::: "memory")

__device__ inline float bf2f(unsigned short u){
  union { unsigned int i; float f; } v; v.i = ((unsigned int)u) << 16; return v.f;
}
__device__ inline unsigned short f2bf(float f){
  union { float f; unsigned int i; } v; v.f = f;
  unsigned int x = v.i;
  return (unsigned short)((x + 0x7fffu + ((x >> 16) & 1u)) >> 16);
}
__device__ inline float sigm(float x){ return __builtin_amdgcn_rcpf(1.0f + __expf(-x)); }

// ---------------- K0: prep (zeros + a12 cast + full xcast) ----------------
__global__ __launch_bounds__(512) void k_pre(const float* __restrict__ x,
                                             unsigned short* __restrict__ xb,
                                             unsigned short* hl_slot, unsigned short* hg_slot,
                                             const float* A1, const float* A2,
                                             unsigned short* a12)
{
  int i = blockIdx.x * 512 + threadIdx.x;   // grid 256 -> 131072 threads
  hl_slot[i] = 0;
  hg_slot[i] = 0;
  if (i < 32768) a12[i] = f2bf((i < 16384) ? A1[i] : A2[i - 16384]);
  for (int i8 = i; i8 < 200 * 16384; i8 += 131072) {
    int t = i8 >> 14, rem = i8 & 16383, b = rem >> 4, chn = rem & 15;
    const float4* xf = (const float4*)(x + (size_t)t * 131072 + (size_t)b * 128 + chn * 8);
    float4 a = xf[0], bb = xf[1];
    short8 o;
    o[0]=(short)f2bf(a.x); o[1]=(short)f2bf(a.y); o[2]=(short)f2bf(a.z); o[3]=(short)f2bf(a.w);
    o[4]=(short)f2bf(bb.x); o[5]=(short)f2bf(bb.y); o[6]=(short)f2bf(bb.z); o[7]=(short)f2bf(bb.w);
    *(short8*)(xb + (size_t)t * 131072 + (size_t)(b >> 4) * 2048 + chn * 128 + (b & 15) * 8) = o;
  }
}

// ---------------- K1: fused dual-GRU scan (R6 verbatim) ----------------
// grid 128 = (64 batch-groups x 2 GRUs), block 512 (8 waves, 16 cols each).
__global__ __launch_bounds__(512, 2) void k_scan(
    const unsigned short* __restrict__ xb,
    const float* __restrict__ Wih_g, const float* __restrict__ Whh_g,
    const float* __restrict__ bih_g, const float* __restrict__ bhh_g,
    const float* __restrict__ Wih_l, const float* __restrict__ Whh_l,
    const float* __restrict__ bih_l, const float* __restrict__ bhh_l,
    unsigned short* __restrict__ hl_seq, unsigned short* __restrict__ hg_seq,
    int tc, int t0)
{
  __shared__ __align__(16) unsigned short hb[2][2048];
  int tid = threadIdx.x;
  int w = tid >> 6, L = tid & 63, l15 = L & 15, q = L >> 4;
  int gru = blockIdx.x & 1;                 // 0 = g, 1 = l
  int bg = blockIdx.x >> 1;                 // batch group (16 rows)
  const float* Wih = gru ? Wih_l : Wih_g;
  const float* Whh = gru ? Whh_l : Whh_g;
  const float* bih = gru ? bih_l : bih_g;
  const float* bhh = gru ? bhh_l : bhh_g;
  unsigned short* myseq = gru ? hl_seq : hg_seq;

  int col = w * 16 + l15;
  int cch = w * 2 + (l15 >> 3);
  int cj  = l15 & 7;

  short8 Wi[3][4], Wh[3][4];
  #pragma unroll
  for (int G = 0; G < 3; G++) {
    int row = G * 128 + col;
    #pragma unroll
    for (int kf = 0; kf < 4; kf++) {
      const float4* p0 = (const float4*)(Wih + (size_t)row * 128 + kf * 32 + q * 8);
      const float4* p1 = (const float4*)(Whh + (size_t)row * 128 + kf * 32 + q * 8);
      float4 a0 = p0[0], a1 = p0[1], b0f = p1[0], b1f = p1[1];
      short8 si, sh;
      si[0]=(short)f2bf(a0.x); si[1]=(short)f2bf(a0.y); si[2]=(short)f2bf(a0.z); si[3]=(short)f2bf(a0.w);
      si[4]=(short)f2bf(a1.x); si[5]=(short)f2bf(a1.y); si[6]=(short)f2bf(a1.z); si[7]=(short)f2bf(a1.w);
      sh[0]=(short)f2bf(b0f.x); sh[1]=(short)f2bf(b0f.y); sh[2]=(short)f2bf(b0f.z); sh[3]=(short)f2bf(b0f.w);
      sh[4]=(short)f2bf(b1f.x); sh[5]=(short)f2bf(b1f.y); sh[6]=(short)f2bf(b1f.z); sh[7]=(short)f2bf(b1f.w);
      Wi[G][kf] = si; Wh[G][kf] = sh;
    }
  }
  float br  = bih[col]       + bhh[col];
  float bz  = bih[128 + col] + bhh[128 + col];
  float bin = bih[256 + col];               // bhh_n stays inside r*( ) per PyTorch GRU
  float bnh = bhh[256 + col];

  float hold[4];
  #pragma unroll
  for (int r = 0; r < 4; r++) {
    int m = q * 4 + r;
    unsigned short u = myseq[(size_t)(tc - 1) * 131072 + (size_t)bg * 2048 + cch * 128 + m * 8 + cj];
    hold[r] = bf2f(u);
    hb[0][cch * 128 + m * 8 + cj] = u;
  }

  short8 x2[2][4];
  const unsigned short* xlane = xb + (size_t)bg * 2048 + q * 128 + l15 * 8;
  {
    const unsigned short* px = xlane + (size_t)t0 * 131072;
    #pragma unroll
    for (int kf = 0; kf < 4; kf++) x2[0][kf] = *(const short8*)(px + kf * 512);
    int t1 = t0 + (tc > 1 ? 1 : 0);
    const unsigned short* py = xlane + (size_t)t1 * 131072;
    #pragma unroll
    for (int kf = 0; kf < 4; kf++) x2[1][kf] = *(const short8*)(py + kf * 512);
  }
  __syncthreads();

  unsigned short* opq = myseq + (size_t)t0 * 131072 + (size_t)bg * 2048 + cch * 128 + q * 32 + cj;
  unsigned int* hbw = (unsigned int*)&hb[0][0];
  int wdw = (2 * w + (l15 >> 3)) * 64 + ((l15 & 6) >> 1);
  bool wlane = (L & 1) == 0;

  auto step = [&](int s, int pin, int pout) {
    short8 Ah[4];
    #pragma unroll
    for (int kf = 0; kf < 4; kf++)
      Ah[kf] = *(const short8*)&hb[pin][(kf * 4 + q) * 128 + l15 * 8];

    // h-side MFMAs first (critical path)
    float4v rh = (float4v){0.f,0.f,0.f,0.f}, zh = rh, nh = rh;
    #pragma unroll
    for (int kf = 0; kf < 4; kf++) rh = __builtin_amdgcn_mfma_f32_16x16x32_bf16(Ah[kf], Wh[0][kf], rh, 0,0,0);
    #pragma unroll
    for (int kf = 0; kf < 4; kf++) zh = __builtin_amdgcn_mfma_f32_16x16x32_bf16(Ah[kf], Wh[1][kf], zh, 0,0,0);
    #pragma unroll
    for (int kf = 0; kf < 4; kf++) nh = __builtin_amdgcn_mfma_f32_16x16x32_bf16(Ah[kf], Wh[2][kf], nh, 0,0,0);

    float4v rx = (float4v){0.f,0.f,0.f,0.f}, zx = rx, nx = rx;
    #pragma unroll
    for (int kf = 0; kf < 4; kf++) rx = __builtin_amdgcn_mfma_f32_16x16x32_bf16(x2[pin][kf], Wi[0][kf], rx, 0,0,0);
    #pragma unroll
    for (int kf = 0; kf < 4; kf++) zx = __builtin_amdgcn_mfma_f32_16x16x32_bf16(x2[pin][kf], Wi[1][kf], zx, 0,0,0);
    #pragma unroll
    for (int kf = 0; kf < 4; kf++) nx = __builtin_amdgcn_mfma_f32_16x16x32_bf16(x2[pin][kf], Wi[2][kf], nx, 0,0,0);

    {
      int t2 = t0 + (s + 2 < tc ? s + 2 : tc - 1);
      const unsigned short* px = xlane + (size_t)t2 * 131072;
      #pragma unroll
      for (int kf = 0; kf < 4; kf++) x2[pin][kf] = *(const short8*)(px + kf * 512);
    }

    unsigned int* hbo = hbw + pout * 1024 + wdw;
    #pragma unroll
    for (int r = 0; r < 4; r++) {
      float er = __expf(-(rh[r] + rx[r] + br));
      float ez = __expf(-(zh[r] + zx[r] + bz));
      float pr = 1.0f + er, pz = 1.0f + ez;
      float inv = __builtin_amdgcn_rcpf(pr * pz);
      float rr = pz * inv;
      float zz = pr * inv;
      float y  = nx[r] + bin + rr * (nh[r] + bnh);
      float em = __expf(-2.0f * y);
      float nn = 2.0f * __builtin_amdgcn_rcpf(1.0f + em) - 1.0f;
      float hn = nn + zz * (hold[r] - nn);
      hold[r] = hn;
      unsigned short hu = f2bf(hn);
      opq[r * 8] = hu;
      unsigned int hv = (unsigned int)hu;
      unsigned int ov = (unsigned int)__shfl_xor((int)hv, 1);
      if (wlane) hbo[(4 * q + r) * 4] = hv | (ov << 16);
    }
    opq += 131072;
    LDS_BARRIER();
  };

  int s = 0;
  for (; s + 1 < tc; s += 2) { step(s, 0, 1); step(s + 1, 1, 0); }
  if (s < tc) step(s, 0, 1);
}

// ---------------- K2: epilogue pass 1 (score + range-local cum) -------------
// grid 256 = (64 bg x 4 ranges of 50 t), block 512 (8 waves).
// waves: cg = w&3 -> n-tiles {2cg,2cg+1}; tg = w>>2 -> t stride 2.
__global__ __launch_bounds__(512, 2) void k_ep1(
    const unsigned short* __restrict__ hl_seq,
    const unsigned short* __restrict__ hg_seq,
    const unsigned short* __restrict__ a12,
    const float* __restrict__ v1,
    const int* __restrict__ lengths,
    float* __restrict__ Rbuf, float* __restrict__ out)
{
  __shared__ float scF4[4 * 800];
  __shared__ __align__(16) unsigned short hlL[8 * 2048];
  int tid = threadIdx.x;
  int bg = blockIdx.x >> 2, rg = blockIdx.x & 3;
  int w = tid >> 6, L = tid & 63, l15 = L & 15, q = L >> 4;
  int cg = w & 3, tg = w >> 2;
  int t0g = rg * 50;

  // register-resident B-fragments (A1^T, A2^T), 2 n-tiles per wave
  short8 B1[2][4], B2[2][4];
  float v1v[2];
  #pragma unroll
  for (int ntl = 0; ntl < 2; ntl++) {
    int g = (2 * cg + ntl) * 16 + l15;
    #pragma unroll
    for (int kf = 0; kf < 4; kf++) {
      B1[ntl][kf] = *(const short8*)(a12 + (size_t)g * 128 + kf * 32 + q * 8);
      B2[ntl][kf] = *(const short8*)(a12 + 16384 + (size_t)g * 128 + kf * 32 + q * 8);
    }
    v1v[ntl] = v1[g];
  }

  // score phase
  for (int tl = tg; tl < 50; tl += 2) {
    size_t base = (size_t)(t0g + tl) * 131072 + (size_t)bg * 2048 + q * 128 + l15 * 8;
    float4v acc[2];
    acc[0] = (float4v){0.f,0.f,0.f,0.f}; acc[1] = acc[0];
    {
      short8 F[4];
      #pragma unroll
      for (int kf = 0; kf < 4; kf++) F[kf] = *(const short8*)(hl_seq + base + kf * 512);
      #pragma unroll
      for (int ntl = 0; ntl < 2; ntl++)
        #pragma unroll
        for (int kf = 0; kf < 4; kf++)
          acc[ntl] = __builtin_amdgcn_mfma_f32_16x16x32_bf16(F[kf], B1[ntl][kf], acc[ntl], 0, 0, 0);
    }
    {
      short8 F[4];
      #pragma unroll
      for (int kf = 0; kf < 4; kf++) F[kf] = *(const short8*)(hg_seq + base + kf * 512);
      #pragma unroll
      for (int ntl = 0; ntl < 2; ntl++)
        #pragma unroll
        for (int kf = 0; kf < 4; kf++)
          acc[ntl] = __builtin_amdgcn_mfma_f32_16x16x32_bf16(F[kf], B2[ntl][kf], acc[ntl], 0, 0, 0);
    }
    #pragma unroll
    for (int r = 0; r < 4; r++) {
      float s = v1v[0] * sigm(acc[0][r]) + v1v[1] * sigm(acc[1][r]);
      s += __shfl_xor(s, 1, 16);
      s += __shfl_xor(s, 2, 16);
      s += __shfl_xor(s, 4, 16);
      s += __shfl_xor(s, 8, 16);
      if (l15 == 0) scF4[cg * 800 + tl * 16 + q * 4 + r] = s;
    }
  }
  __syncthreads();
  for (int i = tid; i < 800; i += 512)
    scF4[i] = scF4[i] + scF4[800 + i] + scF4[1600 + i] + scF4[2400 + i];

  // range-local cum: 2048 (b,j) states over 512 threads (4 each)
  float cacc[4]; int capv[4], bl4[4], j4[4], b4[4], fj4[4];
  #pragma unroll
  for (int k = 0; k < 4; k++) {
    int pi = tid + k * 512;
    int bl = pi & 15, j = (pi >> 4) & 127;
    bl4[k] = bl; j4[k] = j;
    int b = bg * 16 + bl; b4[k] = b;
    cacc[k] = 0.0f;
    capv[k] = lengths[b] - 4;
    fj4[k] = (j >> 3) * 128 + bl * 8 + (j & 7);
  }
  for (int seg = 0; seg < 50; seg += 8) {
    int len = (50 - seg < 8) ? (50 - seg) : 8;
    __syncthreads();                         // 1st iter also orders scF4 reduce
    for (int f8 = tid; f8 < len * 256; f8 += 512) {
      int tt = f8 >> 8, idx = f8 & 255;
      *(short8*)&hlL[tt * 2048 + idx * 8] =
          *(const short8*)(hl_seq + (size_t)(t0g + seg + tt) * 131072 + (size_t)bg * 2048 + idx * 8);
    }
    __syncthreads();
    for (int tt = 0; tt < len; tt++) {
      int tl = seg + tt;
      #pragma unroll
      for (int k = 0; k < 4; k++) {
        float h = bf2f(hlL[tt * 2048 + fj4[k]]);
        cacc[k] += scF4[tl * 16 + bl4[k]] * h;
        int d = (t0g + tl) - capv[k];
        if ((unsigned)d < 4u) {
          float hgv = bf2f(hg_seq[(size_t)(t0g + tl) * 131072 + (size_t)bg * 2048 + fj4[k]]);
          out[((size_t)b4[k] * 4 + d) * 128 + j4[k]] = cacc[k] + hgv;
        }
      }
    }
  }
  #pragma unroll
  for (int k = 0; k < 4; k++)
    Rbuf[(size_t)rg * 131072 + (size_t)b4[k] * 128 + j4[k]] = cacc[k];
}

// ---------------- K3: epilogue pass 2 (add range-prefix to captures) --------
__global__ __launch_bounds__(256) void k_ep2(const int* __restrict__ lengths,
                                             const float* __restrict__ Rbuf,
                                             float* __restrict__ out)
{
  int i = blockIdx.x * 256 + threadIdx.x;   // grid 512 -> 131072
  int b = i >> 7, j = i & 127;
  int len = lengths[b];
  size_t bj = (size_t)b * 128 + j;
  float r0 = Rbuf[bj];
  float r1 = Rbuf[131072 + bj];
  float r2 = Rbuf[262144 + bj];
  float P1 = r0, P2 = r0 + r1, P3 = r0 + r1 + r2;
  #pragma unroll
  for (int d = 0; d < 4; d++) {
    int td = len - 4 + d;
    int rg = td / 50;
    if (rg > 0) {
      float add = (rg == 1) ? P1 : (rg == 2) ? P2 : P3;
      out[((size_t)b * 4 + d) * 128 + j] += add;
    }
  }
}

// ---------------- launch ----------------
extern "C" void kernel_launch(void* const* d_in, const int* in_sizes, int n_in,
                              void* d_out, int out_size, void* d_ws, size_t ws_size,
                              hipStream_t stream)
{
  const float* x     = (const float*)d_in[0];
  const int* lengths = (const int*)d_in[1];
  const float* Wih_g = (const float*)d_in[2];
  const float* Whh_g = (const float*)d_in[3];
  const float* bih_g = (const float*)d_in[4];
  const float* bhh_g = (const float*)d_in[5];
  const float* Wih_l = (const float*)d_in[6];
  const float* Whh_l = (const float*)d_in[7];
  const float* bih_l = (const float*)d_in[8];
  const float* bhh_l = (const float*)d_in[9];
  const float* A1    = (const float*)d_in[10];
  const float* A2    = (const float*)d_in[11];
  const float* v1    = (const float*)d_in[12];
  float* out = (float*)d_out;

  const size_t SEQ = (size_t)200 * 1024 * 128 * 2;   // 52.4 MB each
  size_t need = 65536 + 3 * SEQ + 4 * 524288;        // a12 + xb/hl/hg + Rbuf
  if (need > ws_size) return;

  char* wsb = (char*)d_ws;
  size_t o = 0;
  unsigned short* a12 = (unsigned short*)(wsb + o); o += 65536;
  float* Rbuf         = (float*)(wsb + o);          o += 4 * 524288;
  unsigned short* xb  = (unsigned short*)(wsb + o); o += SEQ;
  unsigned short* hl  = (unsigned short*)(wsb + o); o += SEQ;
  unsigned short* hg  = (unsigned short*)(wsb + o); o += SEQ;

  unsigned short* hl_slot = hl + (size_t)199 * 131072;
  unsigned short* hg_slot = hg + (size_t)199 * 131072;

  k_pre<<<256, 512, 0, stream>>>(x, xb, hl_slot, hg_slot, A1, A2, a12);
  k_scan<<<128, 512, 0, stream>>>(xb, Wih_g, Whh_g, bih_g, bhh_g,
                                  Wih_l, Whh_l, bih_l, bhh_l, hl, hg, 200, 0);
  k_ep1<<<256, 512, 0, stream>>>(hl, hg, a12, v1, lengths, Rbuf, out);
  k_ep2<<<512, 256, 0, stream>>>(lengths, Rbuf, out);
}